// Round 13
// baseline (48.565 us; speedup 1.0000x reference)
//
#include <hip/hip_runtime.h>

// FastFood random features, D=64, fp32 — 32-row LDS tiles.
//
// R12 post-mortem: VGPR 96 vs 104 both = 4 waves/SIMD (occupancy steps at
// 64/128/256) -> st[4] split reverted; base is R11 (47.2us, VGPR 104).
// R13 single change: output stores emitted as inline-asm
// `global_store_dwordx4 ... sc1 nt`. Rationale: FETCH=65MB shows the write
// stream allocates in the 256MB L3 and evicts half of the (fully-fitting)
// 134MB input each pass; plain NT bit alone didn't prevent that (FETCH
// identical with/without __builtin_nontemporal_store). sc1+nt pushes stores
// past the MALL without allocating -> input stays L3-resident, FETCH -> ~0,
// per-replay HBM traffic 201 -> ~134MB.
//
// Structure: 32 rows x 64 cols = 8 KB LDS per wave, 2 waves/block. Lane l
// owns HALF of row rr=l&31 (cols cb..cb+31, cb=32*(l>>5)). FWHT64 = 5
// in-lane stages (col bits 0..4) + bit-5 stage via permlane32_swap (VALU
// pipe; partner = hh ? r.x : r.y, HW-verified R8). Stage order bit0..bit5 ==
// reference fwht order -> bitwise-exact fp32 (absmax 0.0 R8-R12).
//
// Q layout (load/permute/store): chunk c=0..7, lane l <-> row r=4c+(l>>4),
// cols e0..e0+3 (e0=(l&15)*4). LDS swizzle col ^ ((row&15)<<2), 16B-preserving,
// conflict-free for b128; R2 b32 gathers spread banks via the swizzle.
// Same-wave DS program order provides all RAW ordering (tile is wave-private;
// no fences, no barriers). Next tile's globals prefetched after R2.

typedef float f32x4 __attribute__((ext_vector_type(4)));
typedef unsigned u32x2 __attribute__((ext_vector_type(2)));

// Value of v in partner lane l^32 (all 64 lanes active).
__device__ __forceinline__ float partner32(float v, bool hh) {
    const unsigned u = __float_as_uint(v);
    const u32x2 r = __builtin_amdgcn_permlane32_swap(u, u, false, false);
    return __uint_as_float(hh ? r.x : r.y);
}

// Streaming store: bypass L2/MALL allocation (sc1 + nt cache policy).
__device__ __forceinline__ void store_stream(f32x4 v, f32x4* p) {
    asm volatile("global_store_dwordx4 %0, %1, off sc1 nt"
                 :: "v"(p), "v"(v) : "memory");
}

#define FSTAGE32(H)                                                 \
    _Pragma("unroll")                                               \
    for (int i = 0; i < 32; i += 2*(H)) {                           \
        _Pragma("unroll")                                           \
        for (int j = 0; j < (H); ++j) {                             \
            const float a = y[i+j], b = y[i+j+(H)];                 \
            y[i+j] = a + b; y[i+j+(H)] = a - b;                     \
        }                                                           \
    }

__global__ __launch_bounds__(128) void fastfood_kernel(
    const float* __restrict__ x,
    const float* __restrict__ Bv,
    const float* __restrict__ Gv,
    const float* __restrict__ Sv,
    const int*   __restrict__ Pv,
    float* __restrict__ out,
    int ntiles)
{
    __shared__ float lds_all[2 * 2048];   // 16 KB/block: 8 KB per wave
    const int l  = threadIdx.x & 63;
    const int wv = threadIdx.x >> 6;
    float* lds = &lds_all[wv * 2048];

    const int wid    = blockIdx.x * 2 + wv;
    const int nwaves = gridDim.x * 2;

    const int hi = l >> 4;        // 0..3
    const int lo = l & 15;        // 0..15
    const int e0 = lo << 2;       // Q-layout col group
    const int rr = l & 31;        // R-layout row
    const bool hh = (l >= 32);    // R-layout column half
    const int cb = hh ? 32 : 0;   // column base
    const int swzr = (rr & 15) << 2;

    const float c1 = 0.35355339059327373f;  // 64^(-1/4)
    const float c2 = 0.125f;                // sqrt(1/64)

    const float bs0 = Bv[e0+0]*c1, bs1 = Bv[e0+1]*c1, bs2 = Bv[e0+2]*c1, bs3 = Bv[e0+3]*c1;
    const float gg0 = Gv[e0+0],    gg1 = Gv[e0+1],    gg2 = Gv[e0+2],    gg3 = Gv[e0+3];
    const float ss0 = Sv[e0+0]*c2, ss1 = Sv[e0+1]*c2, ss2 = Sv[e0+2]*c2, ss3 = Sv[e0+3]*c2;
    const int   p0  = Pv[e0+0],    p1  = Pv[e0+1],    p2  = Pv[e0+2],    p3  = Pv[e0+3];

    const f32x4* __restrict__ xin  = (const f32x4*)x;
    f32x4* __restrict__       yout = (f32x4*)out;

    int t = wid;
    if (t >= ntiles) return;

    // Prologue: load first tile (32 rows = 512 f32x4, 8 chunks).
    f32x4 st[8];
    {
        const long long tb = (long long)t * 512;
        #pragma unroll
        for (int c = 0; c < 8; ++c) st[c] = xin[tb + c*64 + l];
    }

    for (; t < ntiles; t += nwaves) {
        const long long tb = (long long)t * 512;

        // ---- W1: *B*c1, write Q layout ----
        #pragma unroll
        for (int c = 0; c < 8; ++c) {
            const int r = 4*c + hi;
            f32x4 v = st[c];
            v.x *= bs0; v.y *= bs1; v.z *= bs2; v.w *= bs3;
            *(f32x4*)&lds[r*64 + (e0 ^ ((r & 15) << 2))] = v;
        }

        // ---- R1: lane reads its half-row (cols cb..cb+31 of row rr) ----
        float y[32];
        #pragma unroll
        for (int k = 0; k < 8; ++k) {
            const f32x4 v = *(const f32x4*)&lds[rr*64 + ((cb + 4*k) ^ swzr)];
            y[4*k+0] = v.x; y[4*k+1] = v.y; y[4*k+2] = v.z; y[4*k+3] = v.w;
        }

        // ---- FWHT #1: bits 0..4 in-lane, bit 5 via permlane32_swap ----
        FSTAGE32(1) FSTAGE32(2) FSTAGE32(4) FSTAGE32(8) FSTAGE32(16)
        #pragma unroll
        for (int i = 0; i < 32; ++i) {
            const float opp = partner32(y[i], hh);
            y[i] = hh ? (opp - y[i]) : (y[i] + opp);
        }

        // ---- W2: write y1 back (half-row) ----
        #pragma unroll
        for (int k = 0; k < 8; ++k) {
            f32x4 v;
            v.x = y[4*k+0]; v.y = y[4*k+1]; v.z = y[4*k+2]; v.w = y[4*k+3];
            *(f32x4*)&lds[rr*64 + ((cb + 4*k) ^ swzr)] = v;
        }

        // ---- R2: permuted gather + *G, write Q layout ----
        // (reads of rows 4c..4c+3 precede the write to them: same-wave DS order)
        #pragma unroll
        for (int c = 0; c < 8; ++c) {
            const int r  = 4*c + hi;
            const int rb = r * 64;
            const int sw = (r & 15) << 2;
            const float a0 = lds[rb + (p0 ^ sw)];
            const float a1 = lds[rb + (p1 ^ sw)];
            const float a2 = lds[rb + (p2 ^ sw)];
            const float a3 = lds[rb + (p3 ^ sw)];
            f32x4 v;
            v.x = a0 * gg0; v.y = a1 * gg1; v.z = a2 * gg2; v.w = a3 * gg3;
            *(f32x4*)&lds[rb + (e0 ^ sw)] = v;
        }

        // ---- prefetch next tile (wave-uniform guard) ----
        if (t + nwaves < ntiles) {
            const long long nb = (long long)(t + nwaves) * 512;
            #pragma unroll
            for (int c = 0; c < 8; ++c) st[c] = xin[nb + c*64 + l];
        }

        // ---- R3: read y2 half-row ----
        #pragma unroll
        for (int k = 0; k < 8; ++k) {
            const f32x4 v = *(const f32x4*)&lds[rr*64 + ((cb + 4*k) ^ swzr)];
            y[4*k+0] = v.x; y[4*k+1] = v.y; y[4*k+2] = v.z; y[4*k+3] = v.w;
        }

        // ---- FWHT #2 ----
        FSTAGE32(1) FSTAGE32(2) FSTAGE32(4) FSTAGE32(8) FSTAGE32(16)
        #pragma unroll
        for (int i = 0; i < 32; ++i) {
            const float opp = partner32(y[i], hh);
            y[i] = hh ? (opp - y[i]) : (y[i] + opp);
        }

        // ---- W4: write back (half-row) ----
        #pragma unroll
        for (int k = 0; k < 8; ++k) {
            f32x4 v;
            v.x = y[4*k+0]; v.y = y[4*k+1]; v.z = y[4*k+2]; v.w = y[4*k+3];
            *(f32x4*)&lds[rr*64 + ((cb + 4*k) ^ swzr)] = v;
        }

        // ---- R4: Q read, *S*c2, streaming store (sc1 nt) ----
        #pragma unroll
        for (int c = 0; c < 8; ++c) {
            const int r = 4*c + hi;
            f32x4 v = *(const f32x4*)&lds[r*64 + (e0 ^ ((r & 15) << 2))];
            v.x *= ss0; v.y *= ss1; v.z *= ss2; v.w *= ss3;
            store_stream(v, &yout[tb + c*64 + l]);
        }
    }
}

extern "C" void kernel_launch(void* const* d_in, const int* in_sizes, int n_in,
                              void* d_out, int out_size, void* d_ws, size_t ws_size,
                              hipStream_t stream) {
    const float* x = (const float*)d_in[0];
    const float* B = (const float*)d_in[1];
    const float* G = (const float*)d_in[2];
    const float* S = (const float*)d_in[3];
    const int*   P = (const int*)d_in[4];
    float* out = (float*)d_out;

    const int ntiles = in_sizes[0] / 2048;   // 32 rows x 64 floats per tile

    const int block = 128;   // 2 waves, 16 KB LDS
    const int grid  = 2560;  // 10 blocks/CU; grid-stride over 16384 tiles
    fastfood_kernel<<<grid, block, 0, stream>>>(x, B, G, S, P, out, ntiles);
}

// Round 14
// 47.032 us; speedup vs baseline: 1.0326x; 1.0326x over previous
//
#include <hip/hip_runtime.h>

// FastFood random features, D=64, fp32 — 16-row LDS tiles for 32 waves/CU.
//
// R13 post-mortem: sc1/nt store policy null (L3 allocation is page-attr
// controlled, not instruction) -> 65MB refetch is structural. R11-R13 ledger:
// grid shape, VGPR 96, cache policy all null at 4 waves/SIMD. Remaining lever
// is the VGPR<=64 occupancy step (m69: waves/SIMD halve at 64/128/256;
// R12 proved 96 vs 104 is no step). This version halves the tile to 16 rows
// -> y[16]+st[4] = 32 regs + ~24 misc ~= 58 VGPR -> 8 waves/SIMD, 32/CU
// (HW max; LDS 4KB/wave, 16 blocks/CU). Per-row DS+VALU costs unchanged.
//
// R layout: lane l owns QUARTER of row rr=l&15: cols cq..cq+15 (cq=16*(l>>4)).
// FWHT64 = 4 in-lane stages (col bits 0..3) + bit4 via permlane16_swap
// (partner l^16) + bit5 via permlane32_swap (partner l^32). Partner select
// mirrors the R8 HW-verified 32-swap: partner = (l&K) ? r.x : r.y.
// Stage order bit0..bit5 == reference fwht order -> bitwise-exact fp32.
//
// Q layout (load/permute/store): chunk c=0..3, lane l <-> row r=4c+(l>>4),
// cols e0..e0+3 (e0=(l&15)*4). LDS swizzle col ^ (row<<2) (row<16),
// 16B-preserving. P packed 4x8bit in one u32 (VGPR economy).
// Same-wave DS program order provides all RAW ordering (tile wave-private;
// no fences, no barriers). Next tile prefetched into st[4] after R2.

typedef float f32x4 __attribute__((ext_vector_type(4)));
typedef unsigned u32x2 __attribute__((ext_vector_type(2)));

__device__ __forceinline__ float partner32(float v, bool hb) {
    const unsigned u = __float_as_uint(v);
    const u32x2 r = __builtin_amdgcn_permlane32_swap(u, u, false, false);
    return __uint_as_float(hb ? r.x : r.y);
}

__device__ __forceinline__ float partner16(float v, bool hb, int l) {
#if __has_builtin(__builtin_amdgcn_permlane16_swap)
    const unsigned u = __float_as_uint(v);
    const u32x2 r = __builtin_amdgcn_permlane16_swap(u, u, false, false);
    return __uint_as_float(hb ? r.x : r.y);
#else
    (void)hb; (void)l;
    return __shfl_xor(v, 16);   // DS fallback
#endif
}

#define FSTAGE16(H)                                                 \
    _Pragma("unroll")                                               \
    for (int i = 0; i < 16; i += 2*(H)) {                           \
        _Pragma("unroll")                                           \
        for (int j = 0; j < (H); ++j) {                             \
            const float a = y[i+j], b = y[i+j+(H)];                 \
            y[i+j] = a + b; y[i+j+(H)] = a - b;                     \
        }                                                           \
    }

__global__ __launch_bounds__(128) void fastfood_kernel(
    const float* __restrict__ x,
    const float* __restrict__ Bv,
    const float* __restrict__ Gv,
    const float* __restrict__ Sv,
    const int*   __restrict__ Pv,
    float* __restrict__ out,
    int ntiles)
{
    __shared__ float lds_all[2 * 1024];   // 8 KB/block: 4 KB per wave
    const int l  = threadIdx.x & 63;
    const int wv = threadIdx.x >> 6;
    float* lds = &lds_all[wv * 1024];

    const int wid    = blockIdx.x * 2 + wv;
    const int nwaves = gridDim.x * 2;

    const int hi = l >> 4;        // 0..3
    const int lo = l & 15;        // 0..15
    const int e0 = lo << 2;       // Q-layout col group
    const int rr = l & 15;        // R-layout row (16 rows)
    const int cq = hi << 4;       // R-layout col base (quarter)
    const int swzr = rr << 2;     // swizzle for row rr
    const bool h16 = (l & 16) != 0;
    const bool h32 = (l & 32) != 0;

    const float c1 = 0.35355339059327373f;  // 64^(-1/4)
    const float c2 = 0.125f;                // sqrt(1/64)

    const float bs0 = Bv[e0+0]*c1, bs1 = Bv[e0+1]*c1, bs2 = Bv[e0+2]*c1, bs3 = Bv[e0+3]*c1;
    const float gg0 = Gv[e0+0],    gg1 = Gv[e0+1],    gg2 = Gv[e0+2],    gg3 = Gv[e0+3];
    const float ss0 = Sv[e0+0]*c2, ss1 = Sv[e0+1]*c2, ss2 = Sv[e0+2]*c2, ss3 = Sv[e0+3]*c2;
    // P packed: 4 x 8-bit (values < 64)
    const unsigned pp = (unsigned)Pv[e0+0] | ((unsigned)Pv[e0+1] << 8)
                      | ((unsigned)Pv[e0+2] << 16) | ((unsigned)Pv[e0+3] << 24);

    const f32x4* __restrict__ xin  = (const f32x4*)x;
    f32x4* __restrict__       yout = (f32x4*)out;

    int t = wid;
    if (t >= ntiles) return;

    // Prologue: load first tile (16 rows = 256 f32x4, 4 chunks).
    f32x4 st[4];
    {
        const long long tb = (long long)t * 256;
        #pragma unroll
        for (int c = 0; c < 4; ++c) st[c] = xin[tb + c*64 + l];
    }

    for (; t < ntiles; t += nwaves) {
        const long long tb = (long long)t * 256;

        // ---- W1: *B*c1, write Q layout ----
        #pragma unroll
        for (int c = 0; c < 4; ++c) {
            const int r = 4*c + hi;
            f32x4 v = st[c];
            v.x *= bs0; v.y *= bs1; v.z *= bs2; v.w *= bs3;
            *(f32x4*)&lds[r*64 + (e0 ^ (r << 2))] = v;
        }

        // ---- R1: lane reads its quarter-row (cols cq..cq+15 of row rr) ----
        float y[16];
        #pragma unroll
        for (int k = 0; k < 4; ++k) {
            const f32x4 v = *(const f32x4*)&lds[rr*64 + ((cq + 4*k) ^ swzr)];
            y[4*k+0] = v.x; y[4*k+1] = v.y; y[4*k+2] = v.z; y[4*k+3] = v.w;
        }

        // ---- FWHT #1: bits 0..3 in-lane, bit4 permlane16, bit5 permlane32 ----
        FSTAGE16(1) FSTAGE16(2) FSTAGE16(4) FSTAGE16(8)
        #pragma unroll
        for (int i = 0; i < 16; ++i) {
            const float opp = partner16(y[i], h16, l);
            y[i] = h16 ? (opp - y[i]) : (y[i] + opp);
        }
        #pragma unroll
        for (int i = 0; i < 16; ++i) {
            const float opp = partner32(y[i], h32);
            y[i] = h32 ? (opp - y[i]) : (y[i] + opp);
        }

        // ---- W2: write y1 back (quarter-row) ----
        #pragma unroll
        for (int k = 0; k < 4; ++k) {
            f32x4 v;
            v.x = y[4*k+0]; v.y = y[4*k+1]; v.z = y[4*k+2]; v.w = y[4*k+3];
            *(f32x4*)&lds[rr*64 + ((cq + 4*k) ^ swzr)] = v;
        }

        // ---- R2: permuted gather + *G, write Q layout ----
        // (reads of rows 4c..4c+3 precede the write to them: same-wave DS order)
        #pragma unroll
        for (int c = 0; c < 4; ++c) {
            const int r  = 4*c + hi;
            const int rb = r * 64;
            const int sw = r << 2;
            const float a0 = lds[rb + (((pp      ) & 63u) ^ sw)];
            const float a1 = lds[rb + (((pp >>  8) & 63u) ^ sw)];
            const float a2 = lds[rb + (((pp >> 16) & 63u) ^ sw)];
            const float a3 = lds[rb + (((pp >> 24) & 63u) ^ sw)];
            f32x4 v;
            v.x = a0 * gg0; v.y = a1 * gg1; v.z = a2 * gg2; v.w = a3 * gg3;
            *(f32x4*)&lds[rb + (e0 ^ sw)] = v;
        }

        // ---- prefetch next tile (wave-uniform guard) ----
        if (t + nwaves < ntiles) {
            const long long nb = (long long)(t + nwaves) * 256;
            #pragma unroll
            for (int c = 0; c < 4; ++c) st[c] = xin[nb + c*64 + l];
        }

        // ---- R3: read y2 quarter-row ----
        #pragma unroll
        for (int k = 0; k < 4; ++k) {
            const f32x4 v = *(const f32x4*)&lds[rr*64 + ((cq + 4*k) ^ swzr)];
            y[4*k+0] = v.x; y[4*k+1] = v.y; y[4*k+2] = v.z; y[4*k+3] = v.w;
        }

        // ---- FWHT #2 ----
        FSTAGE16(1) FSTAGE16(2) FSTAGE16(4) FSTAGE16(8)
        #pragma unroll
        for (int i = 0; i < 16; ++i) {
            const float opp = partner16(y[i], h16, l);
            y[i] = h16 ? (opp - y[i]) : (y[i] + opp);
        }
        #pragma unroll
        for (int i = 0; i < 16; ++i) {
            const float opp = partner32(y[i], h32);
            y[i] = h32 ? (opp - y[i]) : (y[i] + opp);
        }

        // ---- W4: write back (quarter-row) ----
        #pragma unroll
        for (int k = 0; k < 4; ++k) {
            f32x4 v;
            v.x = y[4*k+0]; v.y = y[4*k+1]; v.z = y[4*k+2]; v.w = y[4*k+3];
            *(f32x4*)&lds[rr*64 + ((cq + 4*k) ^ swzr)] = v;
        }

        // ---- R4: Q read, *S*c2, nontemporal store ----
        #pragma unroll
        for (int c = 0; c < 4; ++c) {
            const int r = 4*c + hi;
            f32x4 v = *(const f32x4*)&lds[r*64 + (e0 ^ (r << 2))];
            v.x *= ss0; v.y *= ss1; v.z *= ss2; v.w *= ss3;
            __builtin_nontemporal_store(v, &yout[tb + c*64 + l]);
        }
    }
}

extern "C" void kernel_launch(void* const* d_in, const int* in_sizes, int n_in,
                              void* d_out, int out_size, void* d_ws, size_t ws_size,
                              hipStream_t stream) {
    const float* x = (const float*)d_in[0];
    const float* B = (const float*)d_in[1];
    const float* G = (const float*)d_in[2];
    const float* S = (const float*)d_in[3];
    const int*   P = (const int*)d_in[4];
    float* out = (float*)d_out;

    const int ntiles = in_sizes[0] / 1024;   // 16 rows x 64 floats per tile

    const int block = 128;   // 2 waves, 8 KB LDS -> 16 blocks/CU = 32 waves/CU
    const int grid  = 4096;  // 8192 waves x exactly 4 tiles each (32768 tiles)
    fastfood_kernel<<<grid, block, 0, stream>>>(x, B, G, S, P, out, ntiles);
}